// Round 2
// baseline (668.569 us; speedup 1.0000x reference)
//
#include <hip/hip_runtime.h>
#include <cstdint>

#define NIN     2000
#define NRES    50
#define NOUT    500
#define TSTEPS  512
#define NBATCH  64
#define BT      32768   // NBATCH * TSTEPS
#define KPAD    2048    // W k-dim padded (zeros past 2000)
#define NPAD    64      // W n-dim padded (zeros past 50)
#define KSTEPS  63      // 63*32 = 2016 >= 2000; B zero-padded kills k in [2000,2016)
#define KCLAMP  1996    // last valid float4 base within a 2000-float U row

typedef __bf16 bf16x8 __attribute__((ext_vector_type(8)));
typedef float  f32x4  __attribute__((ext_vector_type(4)));

// tanh(x) = 1 - 2/(e^{2x}+1). Overflow-safe without clamping:
// x >> 0: e=inf -> rcp(inf)=0 -> 1 ; x << 0: e=0 -> 1-2 = -1. No NaN path.
__device__ __forceinline__ float fast_tanh(float x) {
  float e = __expf(2.0f * x);
  return fmaf(-2.0f, __builtin_amdgcn_rcpf(e + 1.0f), 1.0f);
}

// x = hi + lo with hi = RN-bf16(x) (lo then exact in fp32, Dekker), lo truncated
// to bf16 (error ~2^-16 relative to x). Inputs here are tanh outputs / small
// uniform weights: no inf/NaN, no rounding overflow.
__device__ __forceinline__ void bf16_split(float x, unsigned short& h, unsigned short& l) {
  unsigned u  = __float_as_uint(x);
  unsigned hb = (u + 0x7FFFu + ((u >> 16) & 1u)) & 0xFFFF0000u;
  h = (unsigned short)(hb >> 16);
  float lo = x - __uint_as_float(hb);
  l = (unsigned short)(__float_as_uint(lo) >> 16);
}

union ABfrag { unsigned short u16[8]; bf16x8 v; };

// ---- kernel 0: split W_in into zero-padded bf16 hi/lo planes [NPAD][KPAD] ----
__global__ __launch_bounds__(256) void prep_kernel(const float* __restrict__ Win,
                                                   unsigned short* __restrict__ Whi,
                                                   unsigned short* __restrict__ Wlo) {
  int idx = blockIdx.x * 256 + threadIdx.x;   // 0 .. NPAD*KPAD-1 (131072)
  int n = idx >> 11;                          // KPAD = 2^11
  int k = idx & (KPAD - 1);
  float x = (n < NRES && k < NIN) ? Win[n * NIN + k] : 0.0f;
  unsigned short h, l;
  bf16_split(x, h, l);
  Whi[idx] = h;
  Wlo[idx] = l;
}

// ---- kernel 1: P[bt][r] = sum_k tanh(U[bt][k]) * W_in[r][k] via 3-pass bf16 MFMA
// UNCHANGED from verified round-1 kernel (isolating the recur rewrite this round).
__global__ __launch_bounds__(256) void proj_mfma(const float* __restrict__ U,
                                                 const unsigned short* __restrict__ Whi,
                                                 const unsigned short* __restrict__ Wlo,
                                                 float* __restrict__ P) {
  const int wave = threadIdx.x >> 6;
  const int lane = threadIdx.x & 63;
  const int mrow = lane & 15;        // A row / C col within tile
  const int g    = lane >> 4;        // k-group (and C row group)
  const int g8   = g * 8;
  const int row0 = (blockIdx.x * 4 + wave) * 16;

  const float* __restrict__ u = U + (size_t)(row0 + mrow) * NIN;

  const unsigned short* bhp[4];
  const unsigned short* blp[4];
#pragma unroll
  for (int f = 0; f < 4; ++f) {
    const int n = f * 16 + mrow;     // B col
    bhp[f] = Whi + n * KPAD + g8;
    blp[f] = Wlo + n * KPAD + g8;
  }

  f32x4 acc[4] = {};

  float4 ca = *(const float4*)(u + min(g8, KCLAMP));
  float4 cb = *(const float4*)(u + min(g8 + 4, KCLAMP));

  for (int s = 0; s < KSTEPS; ++s) {
    const int k0 = s * 32;
    const int kn = k0 + 32;
    // next-step U prefetch (clamped: last iteration's fetch is a safe dup)
    float4 na = *(const float4*)(u + min(kn + g8, KCLAMP));
    float4 nb = *(const float4*)(u + min(kn + g8 + 4, KCLAMP));

    bf16x8 bh[4], bl[4];
#pragma unroll
    for (int f = 0; f < 4; ++f) {
      bh[f] = *(const bf16x8*)(bhp[f] + k0);
      bl[f] = *(const bf16x8*)(blp[f] + k0);
    }

    float t[8];
    t[0] = fast_tanh(ca.x); t[1] = fast_tanh(ca.y);
    t[2] = fast_tanh(ca.z); t[3] = fast_tanh(ca.w);
    t[4] = fast_tanh(cb.x); t[5] = fast_tanh(cb.y);
    t[6] = fast_tanh(cb.z); t[7] = fast_tanh(cb.w);

    ABfrag ah, al;
#pragma unroll
    for (int j = 0; j < 8; ++j) bf16_split(t[j], ah.u16[j], al.u16[j]);

#pragma unroll
    for (int f = 0; f < 4; ++f)
      acc[f] = __builtin_amdgcn_mfma_f32_16x16x32_bf16(ah.v, bh[f], acc[f], 0, 0, 0);
#pragma unroll
    for (int f = 0; f < 4; ++f)
      acc[f] = __builtin_amdgcn_mfma_f32_16x16x32_bf16(al.v, bh[f], acc[f], 0, 0, 0);
#pragma unroll
    for (int f = 0; f < 4; ++f)
      acc[f] = __builtin_amdgcn_mfma_f32_16x16x32_bf16(ah.v, bl[f], acc[f], 0, 0, 0);

    ca = na; cb = nb;
  }

  // C/D layout (verified m89): col = lane&15, row = (lane>>4)*4 + i
#pragma unroll
  for (int f = 0; f < 4; ++f) {
    const int col = f * 16 + mrow;
    if (col < NRES) {
#pragma unroll
      for (int i = 0; i < 4; ++i) {
        const int r = row0 + g * 4 + i;
        P[(size_t)r * NRES + col] = acc[f][i];
      }
    }
  }
}

// ---- kernel 2: sequential recurrence (one wave per batch row) + fused readout ----
// v2: (a) __launch_bounds__(64,1) unlocks the VGPR budget so the W_res row
// (w[52], zero-padded) actually lives in registers — v1 was allocated 44 VGPRs
// and re-materialized W_res from memory EVERY timestep (the 1037 cyc/step stall).
// (b) state broadcast via LDS wide-read: each lane writes state to sbuf[lane];
// 13x ds_read_b128 from wave-uniform addresses broadcast all 50 states to every
// lane (same-address LDS reads are conflict-free) — replaces 50 readlane
// VALU->SGPR->VALU hazard pairs per step.
__global__ __launch_bounds__(64, 1) void recur_kernel(const float* __restrict__ P,
                                                      const float* __restrict__ W_res,
                                                      const float* __restrict__ W_out,
                                                      const float* __restrict__ bias,
                                                      float* __restrict__ out) {
  __shared__ float sbuf[64];
  const int b    = blockIdx.x;
  const int lane = threadIdx.x;
  const int r    = (lane < NRES) ? lane : 0;   // lanes 50-63 mirror lane 0 (never read back)

  // w[52]: this lane's W_res row, padded with zeros at j=50,51 so the broadcast
  // quads can run 13 full float4s (sbuf[50],sbuf[51] hold finite mirror states; x0 = 0).
  float w[52];
#pragma unroll
  for (int j = 0; j < NRES; ++j) w[j] = W_res[r * NRES + j];
  w[50] = 0.0f; w[51] = 0.0f;

  const float* Pb = P + (size_t)b * TSTEPS * NRES;
  float state = 0.0f;

  float pring[8];
#pragma unroll
  for (int i = 0; i < 8; ++i) pring[i] = Pb[i * NRES + r];

#pragma unroll 8
  for (int t = 0; t < TSTEPS; ++t) {
    float pcur = pring[t & 7];
    if (t + 8 < TSTEPS) pring[t & 7] = Pb[(t + 8) * NRES + r];

    sbuf[lane] = state;
    __syncthreads();   // single wave: compiles to lgkmcnt drain + cheap barrier

    // 4-way split accumulator over 13 broadcast quads
    float a0 = pcur, a1 = 0.0f, a2 = 0.0f, a3 = 0.0f;
#pragma unroll
    for (int q = 0; q < 13; ++q) {
      float4 s4 = *(const float4*)&sbuf[q * 4];   // uniform addr -> broadcast b128
      a0 = fmaf(s4.x, w[4 * q + 0], a0);
      a1 = fmaf(s4.y, w[4 * q + 1], a1);
      a2 = fmaf(s4.z, w[4 * q + 2], a2);
      a3 = fmaf(s4.w, w[4 * q + 3], a3);
    }
    state = fast_tanh((a0 + a1) + (a2 + a3));
    // next iteration's sbuf write is data-dependent on these reads (via state),
    // so no extra barrier needed for WAR.
  }

  // readout: out[b][o] = tanh(sum_j state[j] * W_out[j][o] + bias[o])
  sbuf[lane] = state;
  __syncthreads();

#pragma unroll
  for (int kk = 0; kk < 8; ++kk) {
    int o = kk * 64 + lane;
    if (o < NOUT) {
      float a0 = bias[o];
      float a1 = 0.0f;
#pragma unroll
      for (int q = 0; q < 12; ++q) {
        float4 s4 = *(const float4*)&sbuf[q * 4];
        a0 = fmaf(s4.x, W_out[(4 * q + 0) * NOUT + o], a0);
        a1 = fmaf(s4.y, W_out[(4 * q + 1) * NOUT + o], a1);
        a0 = fmaf(s4.z, W_out[(4 * q + 2) * NOUT + o], a0);
        a1 = fmaf(s4.w, W_out[(4 * q + 3) * NOUT + o], a1);
      }
      {  // tail: j = 48, 49 only (W_out has exactly 50 rows)
        float4 s4 = *(const float4*)&sbuf[48];
        a0 = fmaf(s4.x, W_out[48 * NOUT + o], a0);
        a1 = fmaf(s4.y, W_out[49 * NOUT + o], a1);
      }
      out[b * NOUT + o] = fast_tanh(a0 + a1);
    }
  }
}

extern "C" void kernel_launch(void* const* d_in, const int* in_sizes, int n_in,
                              void* d_out, int out_size, void* d_ws, size_t ws_size,
                              hipStream_t stream) {
  const float* inputs = (const float*)d_in[0];
  const float* W_in   = (const float*)d_in[1];
  const float* W_res  = (const float*)d_in[2];
  const float* W_out  = (const float*)d_in[3];
  const float* bias   = (const float*)d_in[4];
  float* out = (float*)d_out;

  // ws layout: P f32 [32768][50] at 0 (6,553,600 B, fully overwritten by proj_mfma),
  // then Whi/Wlo bf16 [64][2048] (262,144 B each). Total ~7.08 MB.
  float* P = (float*)d_ws;
  unsigned short* Whi = (unsigned short*)((char*)d_ws + (size_t)BT * NRES * 4);
  unsigned short* Wlo = Whi + NPAD * KPAD;

  prep_kernel<<<(NPAD * KPAD) / 256, 256, 0, stream>>>(W_in, Whi, Wlo);
  proj_mfma<<<BT / 64, 256, 0, stream>>>(inputs, Whi, Wlo, P);
  recur_kernel<<<NBATCH, 64, 0, stream>>>(P, W_res, W_out, bias, out);
}

// Round 3
// 583.404 us; speedup vs baseline: 1.1460x; 1.1460x over previous
//
#include <hip/hip_runtime.h>
#include <cstdint>

#define NIN     2000
#define NRES    50
#define NOUT    500
#define TSTEPS  512
#define NBATCH  64
#define BT      32768   // NBATCH * TSTEPS
#define KPAD    2048    // W k-dim padded (zeros past 2000)
#define NPAD    64      // W n-dim padded (zeros past 50)
#define KSTEPS  63      // 63*32 = 2016 >= 2000; B zero-padded kills k in [2000,2016)
#define KCLAMP  1996    // last valid float4 base within a 2000-float U row

typedef __bf16 bf16x8 __attribute__((ext_vector_type(8)));
typedef float  f32x4  __attribute__((ext_vector_type(4)));

// tanh(x) = 1 - 2/(e^{2x}+1). Overflow-safe without clamping:
// x >> 0: e=inf -> rcp(inf)=0 -> 1 ; x << 0: e=0 -> 1-2 = -1. No NaN path.
__device__ __forceinline__ float fast_tanh(float x) {
  float e = __expf(2.0f * x);
  return fmaf(-2.0f, __builtin_amdgcn_rcpf(e + 1.0f), 1.0f);
}

// x = hi + lo with hi = RN-bf16(x) (lo then exact in fp32, Dekker), lo truncated
// to bf16 (error ~2^-16 relative to x). Inputs here are tanh outputs / small
// uniform weights: no inf/NaN, no rounding overflow.
__device__ __forceinline__ void bf16_split(float x, unsigned short& h, unsigned short& l) {
  unsigned u  = __float_as_uint(x);
  unsigned hb = (u + 0x7FFFu + ((u >> 16) & 1u)) & 0xFFFF0000u;
  h = (unsigned short)(hb >> 16);
  float lo = x - __uint_as_float(hb);
  l = (unsigned short)(__float_as_uint(lo) >> 16);
}

union ABfrag { unsigned short u16[8]; bf16x8 v; };

// ---- kernel 0: split W_in into zero-padded bf16 hi/lo planes [NPAD][KPAD] ----
__global__ __launch_bounds__(256) void prep_kernel(const float* __restrict__ Win,
                                                   unsigned short* __restrict__ Whi,
                                                   unsigned short* __restrict__ Wlo) {
  int idx = blockIdx.x * 256 + threadIdx.x;   // 0 .. NPAD*KPAD-1 (131072)
  int n = idx >> 11;                          // KPAD = 2^11
  int k = idx & (KPAD - 1);
  float x = (n < NRES && k < NIN) ? Win[n * NIN + k] : 0.0f;
  unsigned short h, l;
  bf16_split(x, h, l);
  Whi[idx] = h;
  Wlo[idx] = l;
}

// ---- kernel 1: P[bt][r] = sum_k tanh(U[bt][k]) * W_in[r][k] via 3-pass bf16 MFMA
// UNCHANGED from verified round-1 kernel (isolating the recur prefetch fix).
__global__ __launch_bounds__(256) void proj_mfma(const float* __restrict__ U,
                                                 const unsigned short* __restrict__ Whi,
                                                 const unsigned short* __restrict__ Wlo,
                                                 float* __restrict__ P) {
  const int wave = threadIdx.x >> 6;
  const int lane = threadIdx.x & 63;
  const int mrow = lane & 15;        // A row / C col within tile
  const int g    = lane >> 4;        // k-group (and C row group)
  const int g8   = g * 8;
  const int row0 = (blockIdx.x * 4 + wave) * 16;

  const float* __restrict__ u = U + (size_t)(row0 + mrow) * NIN;

  const unsigned short* bhp[4];
  const unsigned short* blp[4];
#pragma unroll
  for (int f = 0; f < 4; ++f) {
    const int n = f * 16 + mrow;     // B col
    bhp[f] = Whi + n * KPAD + g8;
    blp[f] = Wlo + n * KPAD + g8;
  }

  f32x4 acc[4] = {};

  float4 ca = *(const float4*)(u + min(g8, KCLAMP));
  float4 cb = *(const float4*)(u + min(g8 + 4, KCLAMP));

  for (int s = 0; s < KSTEPS; ++s) {
    const int k0 = s * 32;
    const int kn = k0 + 32;
    // next-step U prefetch (clamped: last iteration's fetch is a safe dup)
    float4 na = *(const float4*)(u + min(kn + g8, KCLAMP));
    float4 nb = *(const float4*)(u + min(kn + g8 + 4, KCLAMP));

    bf16x8 bh[4], bl[4];
#pragma unroll
    for (int f = 0; f < 4; ++f) {
      bh[f] = *(const bf16x8*)(bhp[f] + k0);
      bl[f] = *(const bf16x8*)(blp[f] + k0);
    }

    float t[8];
    t[0] = fast_tanh(ca.x); t[1] = fast_tanh(ca.y);
    t[2] = fast_tanh(ca.z); t[3] = fast_tanh(ca.w);
    t[4] = fast_tanh(cb.x); t[5] = fast_tanh(cb.y);
    t[6] = fast_tanh(cb.z); t[7] = fast_tanh(cb.w);

    ABfrag ah, al;
#pragma unroll
    for (int j = 0; j < 8; ++j) bf16_split(t[j], ah.u16[j], al.u16[j]);

#pragma unroll
    for (int f = 0; f < 4; ++f)
      acc[f] = __builtin_amdgcn_mfma_f32_16x16x32_bf16(ah.v, bh[f], acc[f], 0, 0, 0);
#pragma unroll
    for (int f = 0; f < 4; ++f)
      acc[f] = __builtin_amdgcn_mfma_f32_16x16x32_bf16(al.v, bh[f], acc[f], 0, 0, 0);
#pragma unroll
    for (int f = 0; f < 4; ++f)
      acc[f] = __builtin_amdgcn_mfma_f32_16x16x32_bf16(ah.v, bl[f], acc[f], 0, 0, 0);

    ca = na; cb = nb;
  }

  // C/D layout (verified m89): col = lane&15, row = (lane>>4)*4 + i
#pragma unroll
  for (int f = 0; f < 4; ++f) {
    const int col = f * 16 + mrow;
    if (col < NRES) {
#pragma unroll
      for (int i = 0; i < 4; ++i) {
        const int r = row0 + g * 4 + i;
        P[(size_t)r * NRES + col] = acc[f][i];
      }
    }
  }
}

// ---- kernel 2: sequential recurrence (one wave per batch row) + fused readout ----
// v3: UNCONDITIONAL 16-deep P-prefetch ring. v1/v2 guarded the ring load with
// `if (t+8 < TSTEPS)`; a conditionally-executed VMEM op makes the outstanding-load
// count path-dependent, so the waitcnt pass must merge conservatively and emits
// s_waitcnt vmcnt(0) before consuming the ring -> EVERY step exposed full
// IF$/HBM latency (~650 cy; measured 1107 cy/step). Unconditional loads keep the
// count static -> counted vmcnt(15), latency amortized /16 (~44 cy/step).
// Tail reads run <=3.2 KB past P's end into the Whi region (same ws allocation).
__global__ __launch_bounds__(64, 1) void recur_kernel(const float* __restrict__ P,
                                                      const float* __restrict__ W_res,
                                                      const float* __restrict__ W_out,
                                                      const float* __restrict__ bias,
                                                      float* __restrict__ out) {
  __shared__ float sbuf[64];
  const int b    = blockIdx.x;
  const int lane = threadIdx.x;
  const int r    = (lane < NRES) ? lane : 0;   // lanes 50-63 mirror lane 0 (never read back)

  // w[52]: this lane's W_res row, zero-padded at j=50,51 so the broadcast loop
  // can run 13 full float4s (sbuf[50],sbuf[51] hold finite mirror states; x0 = 0).
  float w[52];
#pragma unroll
  for (int j = 0; j < NRES; ++j) w[j] = W_res[r * NRES + j];
  w[50] = 0.0f; w[51] = 0.0f;

  const float* Pb = P + (size_t)b * TSTEPS * NRES;
  float state = 0.0f;

  float pring[16];
#pragma unroll
  for (int i = 0; i < 16; ++i) pring[i] = Pb[i * NRES + r];

#pragma unroll 16
  for (int t = 0; t < TSTEPS; ++t) {
    float pcur = pring[t & 15];
    // unconditional refill (see header comment; OOB-by-design reads stay in ws)
    pring[t & 15] = Pb[(t + 16) * NRES + r];

    sbuf[lane] = state;
    __syncthreads();   // single wave: lgkmcnt drain + cheap barrier

    // 13 broadcast quads (uniform-address ds_read_b128), 8-way split accumulator
    float a0 = pcur, a1 = 0.0f, a2 = 0.0f, a3 = 0.0f;
    float a4 = 0.0f, a5 = 0.0f, a6 = 0.0f, a7 = 0.0f;
#pragma unroll
    for (int q = 0; q < 12; q += 2) {
      float4 sA = *(const float4*)&sbuf[q * 4];
      float4 sB = *(const float4*)&sbuf[q * 4 + 4];
      a0 = fmaf(sA.x, w[4 * q + 0], a0);
      a1 = fmaf(sA.y, w[4 * q + 1], a1);
      a2 = fmaf(sA.z, w[4 * q + 2], a2);
      a3 = fmaf(sA.w, w[4 * q + 3], a3);
      a4 = fmaf(sB.x, w[4 * q + 4], a4);
      a5 = fmaf(sB.y, w[4 * q + 5], a5);
      a6 = fmaf(sB.z, w[4 * q + 6], a6);
      a7 = fmaf(sB.w, w[4 * q + 7], a7);
    }
    {
      float4 sA = *(const float4*)&sbuf[48];
      a0 = fmaf(sA.x, w[48], a0);
      a1 = fmaf(sA.y, w[49], a1);
      a2 = fmaf(sA.z, w[50], a2);   // w[50] = 0
      a3 = fmaf(sA.w, w[51], a3);   // w[51] = 0
    }
    state = fast_tanh(((a0 + a1) + (a2 + a3)) + ((a4 + a5) + (a6 + a7)));
    // next iteration's sbuf write is data-dependent on these reads (via state):
    // no extra barrier needed for WAR.
  }

  // readout: out[b][o] = tanh(sum_j state[j] * W_out[j][o] + bias[o])
  sbuf[lane] = state;
  __syncthreads();

#pragma unroll
  for (int kk = 0; kk < 8; ++kk) {
    int o = kk * 64 + lane;
    if (o < NOUT) {
      float a0 = bias[o];
      float a1 = 0.0f;
#pragma unroll
      for (int q = 0; q < 12; ++q) {
        float4 s4 = *(const float4*)&sbuf[q * 4];
        a0 = fmaf(s4.x, W_out[(4 * q + 0) * NOUT + o], a0);
        a1 = fmaf(s4.y, W_out[(4 * q + 1) * NOUT + o], a1);
        a0 = fmaf(s4.z, W_out[(4 * q + 2) * NOUT + o], a0);
        a1 = fmaf(s4.w, W_out[(4 * q + 3) * NOUT + o], a1);
      }
      {  // tail: j = 48, 49 only (W_out has exactly 50 rows)
        float4 s4 = *(const float4*)&sbuf[48];
        a0 = fmaf(s4.x, W_out[48 * NOUT + o], a0);
        a1 = fmaf(s4.y, W_out[49 * NOUT + o], a1);
      }
      out[b * NOUT + o] = fast_tanh(a0 + a1);
    }
  }
}

extern "C" void kernel_launch(void* const* d_in, const int* in_sizes, int n_in,
                              void* d_out, int out_size, void* d_ws, size_t ws_size,
                              hipStream_t stream) {
  const float* inputs = (const float*)d_in[0];
  const float* W_in   = (const float*)d_in[1];
  const float* W_res  = (const float*)d_in[2];
  const float* W_out  = (const float*)d_in[3];
  const float* bias   = (const float*)d_in[4];
  float* out = (float*)d_out;

  // ws layout: P f32 [32768][50] at 0 (6,553,600 B, fully overwritten by proj_mfma),
  // then Whi/Wlo bf16 [64][2048] (262,144 B each). Total ~7.08 MB.
  // NOTE: recur's prefetch ring deliberately over-reads P by <=3.2 KB into Whi.
  float* P = (float*)d_ws;
  unsigned short* Whi = (unsigned short*)((char*)d_ws + (size_t)BT * NRES * 4);
  unsigned short* Wlo = Whi + NPAD * KPAD;

  prep_kernel<<<(NPAD * KPAD) / 256, 256, 0, stream>>>(W_in, Whi, Wlo);
  proj_mfma<<<BT / 64, 256, 0, stream>>>(inputs, Whi, Wlo, P);
  recur_kernel<<<NBATCH, 64, 0, stream>>>(P, W_res, W_out, bias, out);
}